// Round 1
// baseline (334.297 us; speedup 1.0000x reference)
//
#include <hip/hip_runtime.h>

// MeanSquaredError3: heatmap MSE (d1) + offset-regression MSE (d2), scalar out.
//
// Round 3: lane-parallel restructure. Round 2 was LDS/latency-bound: per pair
// it ran a wave-cooperative argmax = 12 dependent ds_bpermute + lgkmcnt(0)
// chains (~1.3k cycles serialized per pair; 448 pairs/CU -> ~160us), 8x the
// ~17us memory floor. Now each LANE owns one (b,j) pair and scans its own
// 196-cell heatmap with a fully-unrolled 49x float4 stream: argmax is a
// per-lane strict-> scan (first-occurrence preserved), tt comes from
// register-resident G columns gy[14]/gx[14] (static indices after unroll -> no
// scratch, no per-cell LDS), and the ox/oy gather issues once per lane at the
// end. Zero cross-lane ops in the hot path; one fp64 wave reduce per block.
// Grid 1792 blocks x 64 threads = 7 blocks/CU exactly (balanced); low
// occupancy is fine because the kernel is a pure HBM stream with 49
// independent loads per lane for the compiler to cluster.
// Arithmetic per element is bit-identical to the round-2 verified kernel.

#define COL 14
#define NJ 14
#define CELLS (COL * COL)     // 196
#define NEGINF -3.402823466e38f

// One heatmap cell: argmax update + masked squared residual.
// CIDX is an unroll-time constant -> cc/COL, cc%COL, gy/gx indices and the
// cc<COL row-0 mask all fold at compile time.
#define CELL1(CIDX, HVAL)                                             \
    {                                                                 \
        const int   cc = (CIDX);                                      \
        const float hh = (HVAL);                                      \
        if (hh > best) { best = hh; bidx = cc; }                      \
        float tt = (gy[cc / COL] * gx[cc % COL] - mnv) * inv;         \
        float dd = hh - tt;                                           \
        if (cc < COL) dd = vise ? dd : 0.0f;                          \
        s1 += dd * dd;                                                \
    }

__global__ __launch_bounds__(64)
void mse3_main(const float* __restrict__ outp, const float* __restrict__ tp,
               const float* __restrict__ vp, double* __restrict__ partial, int npair)
{
    __shared__ float Gs[CELLS];
    __shared__ float cminS[COL], cmaxS[COL];
    const int lane = threadIdx.x;  // 64 threads = 1 wave per block

    // Build G exactly like the reference: w = exp(-0.5*k^2) fp64, normalized,
    // symmetric-padded identity convolution, accumulated fp64, cast to f32.
    for (int cell = lane; cell < CELLS; cell += 64) {
        const double wraw[9] = {3.3546262790251185e-4, 1.1108996538242306e-2,
                                1.353352832366127e-1,  6.065306597126334e-1, 1.0,
                                6.065306597126334e-1,  1.353352832366127e-1,
                                1.1108996538242306e-2, 3.3546262790251185e-4};
        const double Z = 2.5066208042307818;  // sum of wraw
        int gi = cell / COL;
        int gj = cell - COL * gi;
        double a = 0.0;
#pragma unroll
        for (int k = 0; k < 9; ++k) {
            int r = gi + k;  // row into symmetric-padded eye (22 rows)
            int m = (r < 4) ? (3 - r) : ((r < 18) ? (r - 4) : (31 - r));
            if (m == gj) a += wraw[k] / Z;
        }
        Gs[cell] = (float)a;
    }
    __syncthreads();
    // Per-column min/max (all G entries > 0: outer-product min/max factorize;
    // fp multiply is monotone, so factored fp32 min/max == elementwise).
    if (lane < COL) {
        float mn = Gs[lane], mx = mn;
        for (int r = 1; r < COL; ++r) {
            float g = Gs[r * COL + lane];
            mn = fminf(mn, g);
            mx = fmaxf(mx, g);
        }
        cminS[lane] = mn;
        cmaxS[lane] = mx;
    }
    __syncthreads();

    const int p = blockIdx.x * 64 + lane;  // one pair per lane
    float s1 = 0.0f, s2 = 0.0f, cnt = 0.0f, n2 = 0.0f;

    if (p < npair) {
        float2 tv = reinterpret_cast<const float2*>(tp)[p];
        float2 vv = reinterpret_cast<const float2*>(vp)[p];
        int xi = (int)(tv.x * 14.0f);   // trunc toward 0, as astype(int32)
        int yi = (int)(tv.y * 14.0f);
        bool inb    = (xi >= 0) && (xi <= COL - 1) && (yi >= 0) && (yi <= COL - 1);
        bool vis    = ((int)vv.x == 1);
        bool scat   = vis && inb;
        bool zeroed = vis && !inb;
        float ve0   = zeroed ? 0.0f : vv.x;
        float ve1   = zeroed ? 0.0f : vv.y;
        bool  vise  = ((int)ve0 == 1);
        int xic = min(max(xi, 0), COL - 1);
        int yic = min(max(yi, 0), COL - 1);

        // G columns for this pair into registers (static indices after unroll).
        float gy[COL], gx[COL];
#pragma unroll
        for (int r = 0; r < COL; ++r) {
            gy[r] = Gs[r * COL + yic];
            gx[r] = Gs[r * COL + xic];
        }
        float mnq = cminS[yic] * cminS[xic];
        float mxq = cmaxS[yic] * cmaxS[xic];
        // !scat -> mnv=inv=0 -> tt == 0.0 exactly (same result as round-2 path).
        float mnv = scat ? mnq : 0.0f;
        float inv = scat ? 1.0f / (mxq - mnq) : 0.0f;

        int b = p / NJ, j = p - NJ * b;
        const float4* h4p = reinterpret_cast<const float4*>(
            outp + ((size_t)b * (3 * NJ) + j) * CELLS);

        float best = NEGINF;
        int   bidx = 0;
#pragma unroll
        for (int k = 0; k < 49; ++k) {
            float4 hq = h4p[k];     // 49 independent loads; compiler clusters
            CELL1(4 * k + 0, hq.x);
            CELL1(4 * k + 1, hq.y);
            CELL1(4 * k + 2, hq.z);
            CELL1(4 * k + 3, hq.w);
        }

        // Deferred ox/oy gather at the argmax cell (one round trip per pair).
        const float* ob = outp + (size_t)b * (3 * NJ) * CELLS;
        float ox = ob[(size_t)(NJ + j) * CELLS + bidx];
        float oy = ob[(size_t)(2 * NJ + j) * CELLS + bidx];
        int yc = bidx / COL;
        int xc = bidx - COL * yc;
        const float SC = (float)(1.0 / 14.0);
        float dx = (ox + (float)xc) * SC - tv.x; dx *= ve0;
        float dy = (oy + (float)yc) * SC - tv.y; dy *= ve1;
        s2  = dx * dx + dy * dy;
        cnt = vise ? 1.0f : 0.0f;
        n2  = ve0 + ve1;
    }

    // One fp64 wave reduction per block (only cross-lane traffic in the kernel).
    double r0 = (double)s1, r1 = (double)s2, r2 = (double)cnt, r3 = (double)n2;
#pragma unroll
    for (int off = 32; off >= 1; off >>= 1) {
        r0 += __shfl_down(r0, off, 64);
        r1 += __shfl_down(r1, off, 64);
        r2 += __shfl_down(r2, off, 64);
        r3 += __shfl_down(r3, off, 64);
    }
    if (lane == 0) {
        double* o = partial + (size_t)blockIdx.x * 4;
        o[0] = r0; o[1] = r1; o[2] = r2; o[3] = r3;
    }
}

__global__ __launch_bounds__(256)
void mse3_final(const double* __restrict__ partial, float* __restrict__ o, int nblk)
{
    __shared__ double p2[4][4];
    double a0 = 0, a1 = 0, a2 = 0, a3 = 0;
    for (int b = threadIdx.x; b < nblk; b += 256) {
        const double* q = partial + (size_t)b * 4;
        a0 += q[0]; a1 += q[1]; a2 += q[2]; a3 += q[3];
    }
#pragma unroll
    for (int off = 32; off >= 1; off >>= 1) {
        a0 += __shfl_down(a0, off, 64);
        a1 += __shfl_down(a1, off, 64);
        a2 += __shfl_down(a2, off, 64);
        a3 += __shfl_down(a3, off, 64);
    }
    const int lane = threadIdx.x & 63, wv = threadIdx.x >> 6;
    if (lane == 0) { p2[wv][0] = a0; p2[wv][1] = a1; p2[wv][2] = a2; p2[wv][3] = a3; }
    __syncthreads();
    if (threadIdx.x == 0) {
        double s1 = 0, s2 = 0, cn = 0, nn = 0;
        for (int i = 0; i < 4; ++i) {
            s1 += p2[i][0]; s2 += p2[i][1]; cn += p2[i][2]; nn += p2[i][3];
        }
        o[0] = (float)(s1 / cn + s2 / (0.5 * nn));  // d1 + d2
    }
}

extern "C" void kernel_launch(void* const* d_in, const int* in_sizes, int n_in,
                              void* d_out, int out_size, void* d_ws, size_t ws_size,
                              hipStream_t stream)
{
    const float* outp = (const float*)d_in[0];   // (B, 42, 14, 14) f32
    const float* tp   = (const float*)d_in[1];   // (B, 14, 2) f32
    const float* vp   = (const float*)d_in[2];   // (B, 14, 2) f32
    double* partial = (double*)d_ws;             // nblk*4 doubles (~57 KB)

    const int B = in_sizes[0] / (3 * NJ * CELLS);
    const int npair = B * NJ;
    const int nblk = (npair + 63) / 64;          // 1792 for B=8192

    mse3_main<<<nblk, 64, 0, stream>>>(outp, tp, vp, partial, npair);
    mse3_final<<<1, 256, 0, stream>>>(partial, (float*)d_out, nblk);
}